// Round 2
// baseline (1593.323 us; speedup 1.0000x reference)
//
#include <hip/hip_runtime.h>

// ---------------------------------------------------------------------------
// Fused MHA block, fp32 baseline (round 1 — QKV batched into one dispatch).
//   B=2, S=2048, D=1024, H=16, DK=64.
//   d_out = [x+proj_out : 4,194,304 floats][attn : 134,217,728 floats]
//   ws: normed(4M) Q(4M) K(4M) V(4M) floats; ctx reuses normed. 64 MB total.
// ---------------------------------------------------------------------------

#define S_LEN 2048
#define DMODEL 1024
#define NHEAD 16
#define HDIM 64
#define NBATCH 2
#define MROWS (NBATCH * S_LEN) // 4096
#define RMS_EPS 1.1920929e-07f

// ---------------- RMSNorm ----------------
__global__ __launch_bounds__(256) void rmsnorm_k(const float* __restrict__ x,
                                                 const float* __restrict__ g,
                                                 float* __restrict__ out) {
  int row = blockIdx.x;
  int tid = threadIdx.x;
  const float4* xr = (const float4*)(x + (size_t)row * DMODEL);
  float4 v = xr[tid];
  float ss = v.x * v.x + v.y * v.y + v.z * v.z + v.w * v.w;
#pragma unroll
  for (int o = 32; o > 0; o >>= 1) ss += __shfl_xor(ss, o);
  __shared__ float red[4];
  int wid = tid >> 6, lane = tid & 63;
  if (lane == 0) red[wid] = ss;
  __syncthreads();
  float tot = red[0] + red[1] + red[2] + red[3];
  float rs = rsqrtf(tot * (1.0f / DMODEL) + RMS_EPS);
  const float4* gr = (const float4*)g;
  float4 gv = gr[tid];
  float4 o4;
  o4.x = v.x * rs * gv.x;
  o4.y = v.y * rs * gv.y;
  o4.z = v.z * rs * gv.z;
  o4.w = v.w * rs * gv.w;
  ((float4*)(out + (size_t)row * DMODEL))[tid] = o4;
}

// ---------------- QKV projection GEMM: C = A @ W^T + bias, z in {Q,K,V} -----
// A[4096,1024] row-major, W[1024,1024] row-major (torch Linear weight).
// 128x128 tile, k-step 64, 256 thr, 8x8 per thread.
// Thread cols are {tx*4..+3} and {64+tx*4..+3} (2-way-free LDS b128 reads).
// Scatters to [B,H,S,64].
__global__ __launch_bounds__(256) void gemm_qkv(const float* __restrict__ A,
                                                const float* __restrict__ Wq,
                                                const float* __restrict__ bq,
                                                const float* __restrict__ Wk,
                                                const float* __restrict__ bk,
                                                const float* __restrict__ Wv,
                                                const float* __restrict__ bv,
                                                float* __restrict__ Qb,
                                                float* __restrict__ Kb,
                                                float* __restrict__ Vb) {
  __shared__ float As[64][132]; // pad 132: transposed-store 2-way, b128 reads ok
  __shared__ float Bs[64][132];
  const float* W;
  const float* bias;
  float* out;
  if (blockIdx.z == 0) { W = Wq; bias = bq; out = Qb; }
  else if (blockIdx.z == 1) { W = Wk; bias = bk; out = Kb; }
  else { W = Wv; bias = bv; out = Vb; }
  const int m0 = blockIdx.y * 128, n0 = blockIdx.x * 128;
  const int tid = threadIdx.x;
  const int tx = tid & 15, ty = tid >> 4;
  float acc[8][8];
#pragma unroll
  for (int i = 0; i < 8; i++)
#pragma unroll
    for (int j = 0; j < 8; j++) acc[i][j] = 0.f;

  for (int k0 = 0; k0 < 1024; k0 += 64) {
#pragma unroll
    for (int i = 0; i < 8; i++) {
      int v = tid + 256 * i; // 0..2047 float4 slots
      int row = v >> 4, kq = v & 15;
      float4 a = *(const float4*)(A + (size_t)(m0 + row) * 1024 + k0 + kq * 4);
      As[kq * 4 + 0][row] = a.x;
      As[kq * 4 + 1][row] = a.y;
      As[kq * 4 + 2][row] = a.z;
      As[kq * 4 + 3][row] = a.w;
      float4 b = *(const float4*)(W + (size_t)(n0 + row) * 1024 + k0 + kq * 4);
      Bs[kq * 4 + 0][row] = b.x;
      Bs[kq * 4 + 1][row] = b.y;
      Bs[kq * 4 + 2][row] = b.z;
      Bs[kq * 4 + 3][row] = b.w;
    }
    __syncthreads();
#pragma unroll 8
    for (int kk = 0; kk < 64; kk++) {
      float4 a0 = *(const float4*)&As[kk][ty * 8];
      float4 a1 = *(const float4*)&As[kk][ty * 8 + 4];
      float4 b0 = *(const float4*)&Bs[kk][tx * 4];
      float4 b1 = *(const float4*)&Bs[kk][tx * 4 + 64];
      float av[8] = {a0.x, a0.y, a0.z, a0.w, a1.x, a1.y, a1.z, a1.w};
      float bv2[8] = {b0.x, b0.y, b0.z, b0.w, b1.x, b1.y, b1.z, b1.w};
#pragma unroll
      for (int i = 0; i < 8; i++)
#pragma unroll
        for (int j = 0; j < 8; j++) acc[i][j] += av[i] * bv2[j];
    }
    __syncthreads();
  }

  const int c0 = n0 + tx * 4, c1 = n0 + 64 + tx * 4;
  float4 bi0 = *(const float4*)(bias + c0);
  float4 bi1 = *(const float4*)(bias + c1);
#pragma unroll
  for (int i = 0; i < 8; i++) {
    int m = m0 + ty * 8 + i;
    float4 r0 = make_float4(acc[i][0] + bi0.x, acc[i][1] + bi0.y,
                            acc[i][2] + bi0.z, acc[i][3] + bi0.w);
    float4 r1 = make_float4(acc[i][4] + bi1.x, acc[i][5] + bi1.y,
                            acc[i][6] + bi1.z, acc[i][7] + bi1.w);
    int b = m >> 11, s = m & (S_LEN - 1);
    int h0 = c0 >> 6, d0 = c0 & 63;
    int h1 = c1 >> 6, d1 = c1 & 63;
    *(float4*)(out + ((size_t)((b * NHEAD + h0) * S_LEN + s)) * 64 + d0) = r0;
    *(float4*)(out + ((size_t)((b * NHEAD + h1) * S_LEN + s)) * 64 + d1) = r1;
  }
}

// ---------------- O projection: out = ctx @ Wo^T + bo + resid ---------------
__global__ __launch_bounds__(256) void gemm_oproj(const float* __restrict__ A,
                                                  const float* __restrict__ W,
                                                  const float* __restrict__ bias,
                                                  const float* __restrict__ resid,
                                                  float* __restrict__ out) {
  __shared__ float As[64][132];
  __shared__ float Bs[64][132];
  const int m0 = blockIdx.y * 128, n0 = blockIdx.x * 128;
  const int tid = threadIdx.x;
  const int tx = tid & 15, ty = tid >> 4;
  float acc[8][8];
#pragma unroll
  for (int i = 0; i < 8; i++)
#pragma unroll
    for (int j = 0; j < 8; j++) acc[i][j] = 0.f;

  for (int k0 = 0; k0 < 1024; k0 += 64) {
#pragma unroll
    for (int i = 0; i < 8; i++) {
      int v = tid + 256 * i;
      int row = v >> 4, kq = v & 15;
      float4 a = *(const float4*)(A + (size_t)(m0 + row) * 1024 + k0 + kq * 4);
      As[kq * 4 + 0][row] = a.x;
      As[kq * 4 + 1][row] = a.y;
      As[kq * 4 + 2][row] = a.z;
      As[kq * 4 + 3][row] = a.w;
      float4 b = *(const float4*)(W + (size_t)(n0 + row) * 1024 + k0 + kq * 4);
      Bs[kq * 4 + 0][row] = b.x;
      Bs[kq * 4 + 1][row] = b.y;
      Bs[kq * 4 + 2][row] = b.z;
      Bs[kq * 4 + 3][row] = b.w;
    }
    __syncthreads();
#pragma unroll 8
    for (int kk = 0; kk < 64; kk++) {
      float4 a0 = *(const float4*)&As[kk][ty * 8];
      float4 a1 = *(const float4*)&As[kk][ty * 8 + 4];
      float4 b0 = *(const float4*)&Bs[kk][tx * 4];
      float4 b1 = *(const float4*)&Bs[kk][tx * 4 + 64];
      float av[8] = {a0.x, a0.y, a0.z, a0.w, a1.x, a1.y, a1.z, a1.w};
      float bv2[8] = {b0.x, b0.y, b0.z, b0.w, b1.x, b1.y, b1.z, b1.w};
#pragma unroll
      for (int i = 0; i < 8; i++)
#pragma unroll
        for (int j = 0; j < 8; j++) acc[i][j] += av[i] * bv2[j];
    }
    __syncthreads();
  }

  const int c0 = n0 + tx * 4, c1 = n0 + 64 + tx * 4;
  float4 bi0 = *(const float4*)(bias + c0);
  float4 bi1 = *(const float4*)(bias + c1);
#pragma unroll
  for (int i = 0; i < 8; i++) {
    int m = m0 + ty * 8 + i;
    float4 x0 = *(const float4*)(resid + (size_t)m * 1024 + c0);
    float4 x1 = *(const float4*)(resid + (size_t)m * 1024 + c1);
    float4 r0 = make_float4(acc[i][0] + bi0.x + x0.x, acc[i][1] + bi0.y + x0.y,
                            acc[i][2] + bi0.z + x0.z, acc[i][3] + bi0.w + x0.w);
    float4 r1 = make_float4(acc[i][4] + bi1.x + x1.x, acc[i][5] + bi1.y + x1.y,
                            acc[i][6] + bi1.z + x1.z, acc[i][7] + bi1.w + x1.w);
    *(float4*)(out + (size_t)m * 1024 + c0) = r0;
    *(float4*)(out + (size_t)m * 1024 + c1) = r1;
  }
}

// ---------------- scores: S = Q @ K^T * 1/8, per (b,h) batch ----------------
// Writes raw scaled scores into attn region; blocks fully above diagonal skip.
// Softmax kernel later masks k>q, so no masking needed here.
__global__ __launch_bounds__(256) void gemm_scores(const float* __restrict__ Q,
                                                   const float* __restrict__ Kt,
                                                   float* __restrict__ attn) {
  const int bh = blockIdx.z;
  const int m0 = blockIdx.y * 128, n0 = blockIdx.x * 128;
  if (n0 > m0) return; // entire block masked (n0 >= m0+128 > q for all rows)
  __shared__ float As[64][132];
  __shared__ float Bs[64][132];
  const float* Qp = Q + (size_t)bh * S_LEN * 64;
  const float* Kp = Kt + (size_t)bh * S_LEN * 64;
  const int tid = threadIdx.x, tx = tid & 15, ty = tid >> 4;
  float acc[8][8];
#pragma unroll
  for (int i = 0; i < 8; i++)
#pragma unroll
    for (int j = 0; j < 8; j++) acc[i][j] = 0.f;

#pragma unroll
  for (int i = 0; i < 8; i++) {
    int v = tid + 256 * i;
    int row = v >> 4, kq = v & 15;
    float4 a = *(const float4*)(Qp + (size_t)(m0 + row) * 64 + kq * 4);
    As[kq * 4 + 0][row] = a.x;
    As[kq * 4 + 1][row] = a.y;
    As[kq * 4 + 2][row] = a.z;
    As[kq * 4 + 3][row] = a.w;
    float4 b = *(const float4*)(Kp + (size_t)(n0 + row) * 64 + kq * 4);
    Bs[kq * 4 + 0][row] = b.x;
    Bs[kq * 4 + 1][row] = b.y;
    Bs[kq * 4 + 2][row] = b.z;
    Bs[kq * 4 + 3][row] = b.w;
  }
  __syncthreads();
#pragma unroll 8
  for (int kk = 0; kk < 64; kk++) {
    float4 a0 = *(const float4*)&As[kk][ty * 8];
    float4 a1 = *(const float4*)&As[kk][ty * 8 + 4];
    float4 b0 = *(const float4*)&Bs[kk][tx * 4];
    float4 b1 = *(const float4*)&Bs[kk][tx * 4 + 64];
    float av[8] = {a0.x, a0.y, a0.z, a0.w, a1.x, a1.y, a1.z, a1.w};
    float bv2[8] = {b0.x, b0.y, b0.z, b0.w, b1.x, b1.y, b1.z, b1.w};
#pragma unroll
    for (int i = 0; i < 8; i++)
#pragma unroll
      for (int j = 0; j < 8; j++) acc[i][j] += av[i] * bv2[j];
  }
  float* Cp = attn + (size_t)bh * S_LEN * S_LEN;
#pragma unroll
  for (int i = 0; i < 8; i++) {
    int m = m0 + ty * 8 + i;
    float4 r0 = make_float4(acc[i][0] * 0.125f, acc[i][1] * 0.125f,
                            acc[i][2] * 0.125f, acc[i][3] * 0.125f);
    float4 r1 = make_float4(acc[i][4] * 0.125f, acc[i][5] * 0.125f,
                            acc[i][6] * 0.125f, acc[i][7] * 0.125f);
    *(float4*)(Cp + (size_t)m * S_LEN + n0 + tx * 4) = r0;
    *(float4*)(Cp + (size_t)m * S_LEN + n0 + 64 + tx * 4) = r1;
  }
}

// ---------------- row softmax with causal mask (in-place on attn) -----------
__global__ __launch_bounds__(256) void softmax_k(float* __restrict__ attn) {
  const int q = blockIdx.x, bh = blockIdx.y;
  float* row = attn + (size_t)bh * S_LEN * S_LEN + (size_t)q * S_LEN;
  const int tid = threadIdx.x;
  float4 t[2];
  float m = -3.0e38f;
#pragma unroll
  for (int i = 0; i < 2; i++) {
    int k4 = tid + 256 * i;
    int k = k4 << 2;
    float4 v;
    if (k <= q) { // this float4 lies in a written scores block
      v = ((const float4*)row)[k4];
      if (k + 1 > q) v.y = -3.0e38f;
      if (k + 2 > q) v.z = -3.0e38f;
      if (k + 3 > q) v.w = -3.0e38f;
    } else {
      v = make_float4(-3.0e38f, -3.0e38f, -3.0e38f, -3.0e38f);
    }
    t[i] = v;
    m = fmaxf(m, fmaxf(fmaxf(v.x, v.y), fmaxf(v.z, v.w)));
  }
#pragma unroll
  for (int o = 32; o > 0; o >>= 1) m = fmaxf(m, __shfl_xor(m, o));
  __shared__ float red[4];
  const int wid = tid >> 6, lane = tid & 63;
  if (lane == 0) red[wid] = m;
  __syncthreads();
  m = fmaxf(fmaxf(red[0], red[1]), fmaxf(red[2], red[3]));
  __syncthreads();
  float l = 0.f;
#pragma unroll
  for (int i = 0; i < 2; i++) {
    t[i].x = __expf(t[i].x - m); // masked lanes underflow to exactly 0
    t[i].y = __expf(t[i].y - m);
    t[i].z = __expf(t[i].z - m);
    t[i].w = __expf(t[i].w - m);
    l += t[i].x + t[i].y + t[i].z + t[i].w;
  }
#pragma unroll
  for (int o = 32; o > 0; o >>= 1) l += __shfl_xor(l, o);
  if (lane == 0) red[wid] = l;
  __syncthreads();
  l = red[0] + red[1] + red[2] + red[3];
  const float inv = 1.0f / l;
#pragma unroll
  for (int i = 0; i < 2; i++) {
    int k4 = tid + 256 * i;
    ((float4*)row)[k4] =
        make_float4(t[i].x * inv, t[i].y * inv, t[i].z * inv, t[i].w * inv);
  }
}

// ---------------- PV: ctx = attn @ V, per (b,h); N=64 ----------------------
__global__ __launch_bounds__(256) void pv_k(const float* __restrict__ attn,
                                            const float* __restrict__ V,
                                            float* __restrict__ ctx) {
  const int bh = blockIdx.y;
  const int m0 = blockIdx.x * 128;
  __shared__ float As[64][132];
  __shared__ float Bs[64][68];
  const float* P = attn + (size_t)bh * S_LEN * S_LEN;
  const float* Vp = V + (size_t)bh * S_LEN * 64;
  const int tid = threadIdx.x, tx = tid & 15, ty = tid >> 4;
  const int b = bh >> 4, h = bh & 15;
  float acc[8][4];
#pragma unroll
  for (int i = 0; i < 8; i++)
#pragma unroll
    for (int j = 0; j < 4; j++) acc[i][j] = 0.f;

  const int nkt = m0 / 64 + 2; // covers keys up to m0+127; p==0 beyond q
  for (int t = 0; t < nkt; t++) {
    int k0 = t * 64;
#pragma unroll
    for (int i = 0; i < 8; i++) {
      int v = tid + 256 * i;
      int row = v >> 4, kq = v & 15;
      float4 a = *(const float4*)(P + (size_t)(m0 + row) * S_LEN + k0 + kq * 4);
      As[kq * 4 + 0][row] = a.x;
      As[kq * 4 + 1][row] = a.y;
      As[kq * 4 + 2][row] = a.z;
      As[kq * 4 + 3][row] = a.w;
    }
#pragma unroll
    for (int i = 0; i < 4; i++) {
      int v = tid + 256 * i;
      int kk = v >> 4, dq = v & 15;
      *(float4*)&Bs[kk][dq * 4] =
          *(const float4*)(Vp + (size_t)(k0 + kk) * 64 + dq * 4);
    }
    __syncthreads();
#pragma unroll 8
    for (int kk = 0; kk < 64; kk++) {
      float4 a0 = *(const float4*)&As[kk][ty * 8];
      float4 a1 = *(const float4*)&As[kk][ty * 8 + 4];
      float4 b4 = *(const float4*)&Bs[kk][tx * 4];
      float av[8] = {a0.x, a0.y, a0.z, a0.w, a1.x, a1.y, a1.z, a1.w};
      float bvv[4] = {b4.x, b4.y, b4.z, b4.w};
#pragma unroll
      for (int i = 0; i < 8; i++)
#pragma unroll
        for (int j = 0; j < 4; j++) acc[i][j] += av[i] * bvv[j];
    }
    __syncthreads();
  }
#pragma unroll
  for (int i = 0; i < 8; i++) {
    int q = m0 + ty * 8 + i;
    float4 r = make_float4(acc[i][0], acc[i][1], acc[i][2], acc[i][3]);
    *(float4*)(ctx + ((size_t)(b * S_LEN + q)) * 1024 + h * 64 + tx * 4) = r;
  }
}

// ---------------------------------------------------------------------------
extern "C" void kernel_launch(void* const* d_in, const int* in_sizes, int n_in,
                              void* d_out, int out_size, void* d_ws,
                              size_t ws_size, hipStream_t stream) {
  const float* x = (const float*)d_in[0];
  // d_in[1] = causal mask, statically known (tril) -> unused
  const float* wq = (const float*)d_in[2];
  const float* bq = (const float*)d_in[3];
  const float* wk = (const float*)d_in[4];
  const float* bk = (const float*)d_in[5];
  const float* wv = (const float*)d_in[6];
  const float* bvp = (const float*)d_in[7];
  const float* wo = (const float*)d_in[8];
  const float* bo = (const float*)d_in[9];
  const float* g = (const float*)d_in[10];

  float* out0 = (float*)d_out;                      // [B,S,D] residual output
  float* attn = out0 + (size_t)MROWS * DMODEL;      // [B,H,S,S]

  float* ws = (float*)d_ws;                         // 64 MB used
  float* normed = ws;                               // 4M floats
  float* Qb = ws + (size_t)4 * 1024 * 1024;         // [B,H,S,64]
  float* Kb = ws + (size_t)8 * 1024 * 1024;
  float* Vb = ws + (size_t)12 * 1024 * 1024;
  float* ctx = ws;                                  // reuse normed (dead)

  rmsnorm_k<<<MROWS, 256, 0, stream>>>(x, g, normed);

  dim3 gp(8, 32, 3); // N/128, M/128, {Q,K,V}
  gemm_qkv<<<gp, 256, 0, stream>>>(normed, wq, bq, wk, bk, wv, bvp,
                                   Qb, Kb, Vb);

  dim3 gs(16, 16, 32); // kcol-blocks, qrow-blocks, B*H
  gemm_scores<<<gs, 256, 0, stream>>>(Qb, Kb, attn);

  dim3 gsm(S_LEN, NBATCH * NHEAD);
  softmax_k<<<gsm, 256, 0, stream>>>(attn);

  dim3 gpv(16, 32); // qrow-blocks, B*H
  pv_k<<<gpv, 256, 0, stream>>>(attn, Vb, ctx);

  dim3 go(8, 32); // N/128, M/128
  gemm_oproj<<<go, 256, 0, stream>>>(ctx, wo, bo, x, out0);
}

// Round 3
// 823.065 us; speedup vs baseline: 1.9358x; 1.9358x over previous
//
#include <hip/hip_runtime.h>

// ---------------------------------------------------------------------------
// Fused MHA block, bf16-MFMA pipeline (round 3).
//   B=2, S=2048, D=1024, H=16, DK=64.
//   d_out = [x+proj_out : 4,194,304 f32][attn : 134,217,728 f32]
//   Pipeline: prep(w->bf16) ; rmsnorm(->bf16) ; QKV MFMA GEMM (V transposed);
//             fused 2-pass flash attn (writes attn + ctx) ; oproj MFMA GEMM.
// ---------------------------------------------------------------------------

typedef unsigned short u16;
typedef __attribute__((ext_vector_type(8))) short bf8_t;  // 8 bf16 (4 VGPR)
typedef __attribute__((ext_vector_type(4))) float f4_t;   // MFMA C/D

#define S_LEN 2048
#define NHEAD 16
#define RMS_EPS 1.1920929e-07f

__device__ inline u16 f2bf(float f) {  // round-to-nearest-even
  union { float f; unsigned int i; } v; v.f = f;
  unsigned int r = v.i + 0x7fffu + ((v.i >> 16) & 1u);
  return (u16)(r >> 16);
}

__device__ inline void gll16(const void* g, void* l) {
  __builtin_amdgcn_global_load_lds(
      (const __attribute__((address_space(1))) void*)g,
      (__attribute__((address_space(3))) void*)l, 16, 0, 0);
}

// ---------------- prep: weights fp32 -> bf16 (Wq|Wk|Wv concat, Wo), bias cat
__global__ __launch_bounds__(256) void prep_k(
    const float* __restrict__ wq, const float* __restrict__ wk,
    const float* __restrict__ wv, const float* __restrict__ wo,
    const float* __restrict__ bq, const float* __restrict__ bk,
    const float* __restrict__ bv, u16* __restrict__ Wcat,
    u16* __restrict__ Wob, float* __restrict__ bcat) {
  int idx = blockIdx.x * 256 + threadIdx.x;  // float4 granules
  if (idx < 786432) {  // Wcat: 3*1024*1024/4
    int z = idx / 262144, r = idx - z * 262144;
    const float* s = z == 0 ? wq : z == 1 ? wk : wv;
    float4 v = ((const float4*)s)[r];
    ((ushort4*)Wcat)[idx] =
        make_ushort4(f2bf(v.x), f2bf(v.y), f2bf(v.z), f2bf(v.w));
  } else if (idx < 786432 + 262144) {
    int r = idx - 786432;
    float4 v = ((const float4*)wo)[r];
    ((ushort4*)Wob)[r] = make_ushort4(f2bf(v.x), f2bf(v.y), f2bf(v.z), f2bf(v.w));
  } else if (idx < 786432 + 262144 + 768) {
    int r = idx - (786432 + 262144);
    int z = r >> 8, rr = r & 255;
    const float* s = z == 0 ? bq : z == 1 ? bk : bv;
    ((float4*)bcat)[r] = ((const float4*)s)[rr];
  }
}

// ---------------- RMSNorm -> bf16 ----------------
__global__ __launch_bounds__(256) void rmsnorm_k(const float* __restrict__ x,
                                                 const float* __restrict__ g,
                                                 u16* __restrict__ out) {
  int row = blockIdx.x, tid = threadIdx.x;
  float4 v = ((const float4*)(x + (size_t)row * 1024))[tid];
  float ss = v.x * v.x + v.y * v.y + v.z * v.z + v.w * v.w;
#pragma unroll
  for (int o = 32; o > 0; o >>= 1) ss += __shfl_xor(ss, o);
  __shared__ float red[4];
  int wid = tid >> 6, lane = tid & 63;
  if (lane == 0) red[wid] = ss;
  __syncthreads();
  float rs = rsqrtf((red[0] + red[1] + red[2] + red[3]) * (1.0f / 1024.0f) +
                    RMS_EPS);
  float4 gv = ((const float4*)g)[tid];
  ((ushort4*)(out + (size_t)row * 1024))[tid] =
      make_ushort4(f2bf(v.x * rs * gv.x), f2bf(v.y * rs * gv.y),
                   f2bf(v.z * rs * gv.z), f2bf(v.w * rs * gv.w));
}

// ---------------- bf16 MFMA GEMM, m97-style -------------------------------
// C[m][n] = sum_k A[m][k] * Bm[n][k]  (both row-major, K=1024), 128x128 tile,
// BK=64, 4 waves (2x2), acc 4x4 frags of 16x16x32. LDS linear; global_load_lds.
// MODE 0: + bcat[n]; scatter Q/K -> [b,h,s,64] bf16, V -> [bh][d][s] bf16.
// MODE 1: + bias[n] + resid[m][n] -> fp32 out1[m][n].
template <int MODE>
__global__ __launch_bounds__(256, 2) void gemm_mfma(
    const u16* __restrict__ A, const u16* __restrict__ Bm,
    const float* __restrict__ bias, const float* __restrict__ resid,
    u16* __restrict__ Oq, u16* __restrict__ Ok, u16* __restrict__ Ov,
    float* __restrict__ out1) {
  __shared__ u16 As[128 * 64];
  __shared__ u16 Bs[128 * 64];
  const int m0 = blockIdx.y * 128, n0 = blockIdx.x * 128;
  const int tid = threadIdx.x, l = tid & 63, w = tid >> 6;
  const int wr = w >> 1, wc = w & 1, lg = l >> 4, lo = l & 15;
  const int arow = tid >> 3;           // staging row (0..31, +32/round)
  const int acol = (tid & 7) * 8;      // staging col in bf16

  f4_t acc[4][4];
#pragma unroll
  for (int i = 0; i < 4; i++)
#pragma unroll
    for (int j = 0; j < 4; j++) acc[i][j] = {0.f, 0.f, 0.f, 0.f};

  for (int k0 = 0; k0 < 1024; k0 += 64) {
#pragma unroll
    for (int r = 0; r < 4; r++) {
      gll16(A + (size_t)(m0 + r * 32 + arow) * 1024 + k0 + acol,
            (char*)As + r * 4096 + w * 1024);
      gll16(Bm + (size_t)(n0 + r * 32 + arow) * 1024 + k0 + acol,
            (char*)Bs + r * 4096 + w * 1024);
    }
    __syncthreads();
#pragma unroll
    for (int ks = 0; ks < 2; ks++) {
      bf8_t af[4], bf[4];
#pragma unroll
      for (int mi = 0; mi < 4; mi++)
        af[mi] = *(const bf8_t*)(As + (wr * 64 + mi * 16 + lo) * 64 + ks * 32 +
                                 lg * 8);
#pragma unroll
      for (int ni = 0; ni < 4; ni++)
        bf[ni] = *(const bf8_t*)(Bs + (wc * 64 + ni * 16 + lo) * 64 + ks * 32 +
                                 lg * 8);
#pragma unroll
      for (int mi = 0; mi < 4; mi++)
#pragma unroll
        for (int ni = 0; ni < 4; ni++)
          acc[mi][ni] = __builtin_amdgcn_mfma_f32_16x16x32_bf16(
              af[mi], bf[ni], acc[mi][ni], 0, 0, 0);
    }
    __syncthreads();
  }

  if (MODE == 0) {
    const int z = n0 >> 10;  // 128-wide block never crosses a 1024 boundary
    u16* ob = z == 0 ? Oq : z == 1 ? Ok : Ov;
#pragma unroll
    for (int mi = 0; mi < 4; mi++)
#pragma unroll
      for (int ni = 0; ni < 4; ni++)
#pragma unroll
        for (int j = 0; j < 4; j++) {
          int m = m0 + wr * 64 + mi * 16 + lg * 4 + j;
          int n = n0 + wc * 64 + ni * 16 + lo;
          int nn = n & 1023, h = nn >> 6, d = nn & 63;
          int b = m >> 11, s = m & 2047;
          u16 vv = f2bf(acc[mi][ni][j] + bias[n]);
          if (z < 2)
            ob[(((size_t)(b * 16 + h) * 2048 + s) << 6) + d] = vv;
          else
            ob[((size_t)(b * 16 + h) * 64 + d) * 2048 + s] = vv;  // V^T
        }
  } else {
#pragma unroll
    for (int mi = 0; mi < 4; mi++)
#pragma unroll
      for (int ni = 0; ni < 4; ni++)
#pragma unroll
        for (int j = 0; j < 4; j++) {
          int m = m0 + wr * 64 + mi * 16 + lg * 4 + j;
          int n = n0 + wc * 64 + ni * 16 + lo;
          out1[(size_t)m * 1024 + n] =
              acc[mi][ni][j] + bias[n] + resid[(size_t)m * 1024 + n];
        }
  }
}

// ---------------- fused 2-pass flash attention ------------------------------
// Block: (qt, bh). 4 waves. Scores: wave(wr,wc) = 64q x 64k of a 128x128 tile.
// Pass A: exact per-row (m,l) via online update; K-frags straight from global.
// Pass B: recompute S, P = exp(s-m)/l -> attn (fp32) + P-LDS (bf16);
//         PV: wave(wr,wd=wc) = 64q x 32d, contraction k=128 via P-LDS x Vt-LDS.
__global__ __launch_bounds__(256, 2) void attn_k(
    const u16* __restrict__ Qb, const u16* __restrict__ Kb,
    const u16* __restrict__ Vt, float* __restrict__ attn,
    u16* __restrict__ ctx) {
  const int qt = blockIdx.x, bh = blockIdx.y;
  const int tid = threadIdx.x, l = tid & 63, w = tid >> 6;
  const int wr = w >> 1, wc = w & 1, lg = l >> 4, lo = l & 15;
  const int q0 = qt * 128, nkt = qt + 1;

  __shared__ u16 Pl[128 * 136];   // P tile, pad 136 (row 272B, ~4-way reads)
  __shared__ u16 Vs[64 * 136];    // V^T tile [d][k]
  __shared__ float mred[2][128], lred[2][128];

  const u16* Qp = Qb + (size_t)bh * (2048 * 64);
  const u16* Kp = Kb + (size_t)bh * (2048 * 64);
  const u16* Vp = Vt + (size_t)bh * (64 * 2048);
  float* Ap = attn + (size_t)bh * ((size_t)2048 * 2048);

  // zero-fill masked upper columns [nkt*128, 2048)
  {
    const int c0 = nkt * 128, cols4 = (2048 - c0) >> 2;
    float4 z4 = make_float4(0.f, 0.f, 0.f, 0.f);
    for (int r = 0; r < 128; r++) {
      float4* rp = (float4*)(Ap + (size_t)(q0 + r) * 2048 + c0);
      for (int c = tid; c < cols4; c += 256) rp[c] = z4;
    }
  }

  // Q fragments in registers (reused across all tiles & both passes)
  bf8_t qf[4][2];
#pragma unroll
  for (int mi = 0; mi < 4; mi++)
#pragma unroll
    for (int ks = 0; ks < 2; ks++)
      qf[mi][ks] = *(const bf8_t*)(Qp +
                                   (size_t)(q0 + wr * 64 + mi * 16 + lo) * 64 +
                                   ks * 32 + lg * 8);

  float rm[4][4], rl[4][4];
#pragma unroll
  for (int mi = 0; mi < 4; mi++)
#pragma unroll
    for (int j = 0; j < 4; j++) { rm[mi][j] = -3.0e38f; rl[mi][j] = 0.f; }

  // ---------------- pass A: exact row max & denom ----------------
  for (int kt = 0; kt < nkt; kt++) {
    const int k0 = kt * 128;
    f4_t sa[4][4];
#pragma unroll
    for (int i = 0; i < 4; i++)
#pragma unroll
      for (int j = 0; j < 4; j++) sa[i][j] = {0.f, 0.f, 0.f, 0.f};
#pragma unroll
    for (int ks = 0; ks < 2; ks++) {
      bf8_t kf[4];
#pragma unroll
      for (int ni = 0; ni < 4; ni++)
        kf[ni] = *(const bf8_t*)(Kp +
                                 (size_t)(k0 + wc * 64 + ni * 16 + lo) * 64 +
                                 ks * 32 + lg * 8);
#pragma unroll
      for (int mi = 0; mi < 4; mi++)
#pragma unroll
        for (int ni = 0; ni < 4; ni++)
          sa[mi][ni] = __builtin_amdgcn_mfma_f32_16x16x32_bf16(
              qf[mi][ks], kf[ni], sa[mi][ni], 0, 0, 0);
    }
    const bool diag = (kt == qt);
#pragma unroll
    for (int mi = 0; mi < 4; mi++) {
#pragma unroll
      for (int j = 0; j < 4; j++) {
        const int qrow = q0 + wr * 64 + mi * 16 + lg * 4 + j;
        float sv[4], tmax = -3.0e38f;
#pragma unroll
        for (int ni = 0; ni < 4; ni++) {
          float s = sa[mi][ni][j] * 0.125f;
          if (diag && (k0 + wc * 64 + ni * 16 + lo > qrow)) s = -3.0e38f;
          sv[ni] = s;
          tmax = fmaxf(tmax, s);
        }
        tmax = fmaxf(tmax, __shfl_xor(tmax, 1));
        tmax = fmaxf(tmax, __shfl_xor(tmax, 2));
        tmax = fmaxf(tmax, __shfl_xor(tmax, 4));
        tmax = fmaxf(tmax, __shfl_xor(tmax, 8));
        const float nm = fmaxf(rm[mi][j], tmax);
        float ss = 0.f;
#pragma unroll
        for (int ni = 0; ni < 4; ni++) ss += __expf(sv[ni] - nm);
        ss += __shfl_xor(ss, 1);
        ss += __shfl_xor(ss, 2);
        ss += __shfl_xor(ss, 4);
        ss += __shfl_xor(ss, 8);
        rl[mi][j] = rl[mi][j] * __expf(rm[mi][j] - nm) + ss;
        rm[mi][j] = nm;
      }
    }
  }
  // combine the two k-halves (wc=0/1); bogus all-masked halves vanish via exp
  if (lo == 0) {
#pragma unroll
    for (int mi = 0; mi < 4; mi++)
#pragma unroll
      for (int j = 0; j < 4; j++) {
        int r = wr * 64 + mi * 16 + lg * 4 + j;
        mred[wc][r] = rm[mi][j];
        lred[wc][r] = rl[mi][j];
      }
  }
  __syncthreads();
#pragma unroll
  for (int mi = 0; mi < 4; mi++)
#pragma unroll
    for (int j = 0; j < 4; j++) {
      int r = wr * 64 + mi * 16 + lg * 4 + j;
      float m1 = mred[0][r], m2 = mred[1][r];
      float M = fmaxf(m1, m2);
      float L = lred[0][r] * __expf(m1 - M) + lred[1][r] * __expf(m2 - M);
      rm[mi][j] = M;          // final row max
      rl[mi][j] = 1.0f / L;   // final 1/denominator
    }

  // ---------------- pass B: P write + PV ----------------
  f4_t oa[4][2];
#pragma unroll
  for (int i = 0; i < 4; i++)
#pragma unroll
    for (int j = 0; j < 2; j++) oa[i][j] = {0.f, 0.f, 0.f, 0.f};

  for (int kt = 0; kt < nkt; kt++) {
    const int k0 = kt * 128;
    f4_t sa[4][4];
#pragma unroll
    for (int i = 0; i < 4; i++)
#pragma unroll
      for (int j = 0; j < 4; j++) sa[i][j] = {0.f, 0.f, 0.f, 0.f};
#pragma unroll
    for (int ks = 0; ks < 2; ks++) {
      bf8_t kf[4];
#pragma unroll
      for (int ni = 0; ni < 4; ni++)
        kf[ni] = *(const bf8_t*)(Kp +
                                 (size_t)(k0 + wc * 64 + ni * 16 + lo) * 64 +
                                 ks * 32 + lg * 8);
#pragma unroll
      for (int mi = 0; mi < 4; mi++)
#pragma unroll
        for (int ni = 0; ni < 4; ni++)
          sa[mi][ni] = __builtin_amdgcn_mfma_f32_16x16x32_bf16(
              qf[mi][ks], kf[ni], sa[mi][ni], 0, 0, 0);
    }
    // stage V^T tile [64 d][128 k] (coalesced rows from pre-transposed global)
#pragma unroll
    for (int it = 0; it < 4; it++) {
      int gr = it * 256 + tid, d = gr >> 4, gcol = gr & 15;
      *(int4*)(&Vs[d * 136 + gcol * 8]) =
          *(const int4*)(Vp + (size_t)d * 2048 + k0 + gcol * 8);
    }
    const bool diag = (kt == qt);
#pragma unroll
    for (int mi = 0; mi < 4; mi++) {
#pragma unroll
      for (int j = 0; j < 4; j++) {
        const int qrow = q0 + wr * 64 + mi * 16 + lg * 4 + j;
        const int qloc = wr * 64 + mi * 16 + lg * 4 + j;
        float* arow = Ap + (size_t)qrow * 2048 + k0 + wc * 64;
#pragma unroll
        for (int ni = 0; ni < 4; ni++) {
          float s = sa[mi][ni][j] * 0.125f;
          float p = __expf(s - rm[mi][j]) * rl[mi][j];
          if (diag && (k0 + wc * 64 + ni * 16 + lo > qrow)) p = 0.f;
          arow[ni * 16 + lo] = p;
          Pl[qloc * 136 + wc * 64 + ni * 16 + lo] = f2bf(p);
        }
      }
    }
    __syncthreads();
    // PV: wave (wr, wd=wc): q 64 x d 32, contraction over k=128
#pragma unroll
    for (int ks = 0; ks < 4; ks++) {
      bf8_t pf[4], vf[2];
#pragma unroll
      for (int mi = 0; mi < 4; mi++)
        pf[mi] =
            *(const bf8_t*)(&Pl[(wr * 64 + mi * 16 + lo) * 136 + ks * 32 +
                                lg * 8]);
#pragma unroll
      for (int ni = 0; ni < 2; ni++)
        vf[ni] =
            *(const bf8_t*)(&Vs[(wc * 32 + ni * 16 + lo) * 136 + ks * 32 +
                                lg * 8]);
#pragma unroll
      for (int mi = 0; mi < 4; mi++)
#pragma unroll
        for (int ni = 0; ni < 2; ni++)
          oa[mi][ni] = __builtin_amdgcn_mfma_f32_16x16x32_bf16(
              pf[mi], vf[ni], oa[mi][ni], 0, 0, 0);
    }
    __syncthreads();
  }

  // ctx bf16 [B*S][1024]
  const int b = bh >> 4, h = bh & 15;
#pragma unroll
  for (int mi = 0; mi < 4; mi++)
#pragma unroll
    for (int ni = 0; ni < 2; ni++)
#pragma unroll
      for (int j = 0; j < 4; j++) {
        int q = q0 + wr * 64 + mi * 16 + lg * 4 + j;
        int d = wc * 32 + ni * 16 + lo;
        ctx[(size_t)(b * 2048 + q) * 1024 + h * 64 + d] = f2bf(oa[mi][ni][j]);
      }
}

// ---------------------------------------------------------------------------
extern "C" void kernel_launch(void* const* d_in, const int* in_sizes, int n_in,
                              void* d_out, int out_size, void* d_ws,
                              size_t ws_size, hipStream_t stream) {
  const float* x = (const float*)d_in[0];
  // d_in[1] = causal mask (statically known) -> unused
  const float* wq = (const float*)d_in[2];
  const float* bq = (const float*)d_in[3];
  const float* wk = (const float*)d_in[4];
  const float* bk = (const float*)d_in[5];
  const float* wv = (const float*)d_in[6];
  const float* bv = (const float*)d_in[7];
  const float* wo = (const float*)d_in[8];
  const float* bo = (const float*)d_in[9];
  const float* g = (const float*)d_in[10];

  float* out0 = (float*)d_out;
  float* attn = out0 + (size_t)4096 * 1024;

  u16* nrm = (u16*)d_ws;                    // [4096][1024] bf16
  u16* Wcat = nrm + (size_t)4096 * 1024;    // [3072][1024] bf16
  u16* Wob = Wcat + (size_t)3072 * 1024;    // [1024][1024] bf16
  u16* Qbb = Wob + (size_t)1024 * 1024;     // [2,16,2048,64] bf16
  u16* Kbb = Qbb + (size_t)4194304;
  u16* Vtb = Kbb + (size_t)4194304;         // [32][64][2048] bf16 (V^T)
  u16* ctxb = Vtb + (size_t)4194304;        // [4096][1024] bf16
  float* bcat = (float*)(ctxb + (size_t)4194304);  // [3072] f32

  prep_k<<<4099, 256, 0, stream>>>(wq, wk, wv, wo, bq, bk, bv, Wcat, Wob, bcat);
  rmsnorm_k<<<4096, 256, 0, stream>>>(x, g, nrm);
  gemm_mfma<0><<<dim3(24, 32), 256, 0, stream>>>(nrm, Wcat, bcat, nullptr, Qbb,
                                                 Kbb, Vtb, nullptr);
  attn_k<<<dim3(16, 32), 256, 0, stream>>>(Qbb, Kbb, Vtb, attn, ctxb);
  gemm_mfma<1><<<dim3(8, 32), 256, 0, stream>>>(ctxb, Wob, bo, x, nullptr,
                                                nullptr, nullptr, out0);
}